// Round 1
// baseline (993.438 us; speedup 1.0000x reference)
//
#include <hip/hip_runtime.h>
#include <hip/hip_bf16.h>

#define DD   1024
#define HH   16
#define DHH  64
#define SS   2048
#define BB   2

// ---------------------------------------------------------------------------
// Kernel 1: per-head QKV projection.
// Block = 256 threads, computes Q,K,V tiles of 64 rows x 64 cols for one
// (b, h, q-tile). X tile shared across the 3 outputs; W staged transposed
// ([e][d]) so inner loop is all float4 LDS reads. 4x4 register blocking with
// row/col indices strided by 16 to keep bank conflicts <=2-way.
// ---------------------------------------------------------------------------
__global__ __launch_bounds__(256) void proj_kernel(
    const float* __restrict__ X,
    const float* __restrict__ Wq, const float* __restrict__ Wk, const float* __restrict__ Wv,
    const float* __restrict__ bq, const float* __restrict__ bk, const float* __restrict__ bv,
    float* __restrict__ Qo, float* __restrict__ Ko, float* __restrict__ Vo)
{
    const int qt = blockIdx.x, h = blockIdx.y, b = blockIdx.z;
    const int q0 = qt * 64;
    __shared__ float Xs[64][68];
    __shared__ float Wt[3][64][68];   // [mat][e][d]
    const int t  = threadIdx.x;
    const int tg = t >> 4;            // 0..15 (row group)
    const int tc = t & 15;            // 0..15 (col group)

    float acc[3][4][4];
#pragma unroll
    for (int m = 0; m < 3; m++)
#pragma unroll
        for (int ri = 0; ri < 4; ri++)
#pragma unroll
            for (int ei = 0; ei < 4; ei++) acc[m][ri][ei] = 0.f;

    const float* Wm[3] = { Wq + (size_t)h * DD * DHH,
                           Wk + (size_t)h * DD * DHH,
                           Wv + (size_t)h * DD * DHH };

    for (int d0 = 0; d0 < DD; d0 += 64) {
        __syncthreads();
        // stage X tile [64 rows][64 d]
#pragma unroll
        for (int i = 0; i < 4; i++) {
            int flat = t + 256 * i;        // 0..1023 float4 slots
            int row  = flat >> 4;
            int c4   = flat & 15;
            float4 x = *(const float4*)(X + ((size_t)(b * SS + q0 + row)) * DD + d0 + c4 * 4);
            *(float4*)&Xs[row][c4 * 4] = x;
        }
        // stage W tiles transposed: Wt[m][e][d]
#pragma unroll
        for (int m = 0; m < 3; m++) {
#pragma unroll
            for (int i = 0; i < 4; i++) {
                int flat = t + 256 * i;
                int dr   = flat >> 4;       // d within chunk
                int c4   = flat & 15;       // e quad
                float4 w = *(const float4*)(Wm[m] + (size_t)(d0 + dr) * DHH + c4 * 4);
                Wt[m][c4 * 4 + 0][dr] = w.x;
                Wt[m][c4 * 4 + 1][dr] = w.y;
                Wt[m][c4 * 4 + 2][dr] = w.z;
                Wt[m][c4 * 4 + 3][dr] = w.w;
            }
        }
        __syncthreads();

        for (int dd = 0; dd < 64; dd += 4) {
            float4 xv[4];
#pragma unroll
            for (int ri = 0; ri < 4; ri++) xv[ri] = *(float4*)&Xs[tg + 16 * ri][dd];
#pragma unroll
            for (int m = 0; m < 3; m++) {
#pragma unroll
                for (int ei = 0; ei < 4; ei++) {
                    float4 wv = *(float4*)&Wt[m][tc + 16 * ei][dd];
#pragma unroll
                    for (int ri = 0; ri < 4; ri++) {
                        acc[m][ri][ei] += xv[ri].x * wv.x + xv[ri].y * wv.y
                                        + xv[ri].z * wv.z + xv[ri].w * wv.w;
                    }
                }
            }
        }
    }

    float* outp[3] = { Qo, Ko, Vo };
    const float* bp[3] = { bq, bk, bv };
#pragma unroll
    for (int m = 0; m < 3; m++) {
#pragma unroll
        for (int ei = 0; ei < 4; ei++) {
            float bias = bp[m][h * DHH + tc + 16 * ei];
#pragma unroll
            for (int ri = 0; ri < 4; ri++) {
                int r = tg + 16 * ri;
                outp[m][(((size_t)(b * HH + h)) * SS + q0 + r) * DHH + tc + 16 * ei] =
                    acc[m][ri][ei] + bias;
            }
        }
    }
}

// ---------------------------------------------------------------------------
// Kernel 2: flash-style attention with FULL-ROW softmax stats (reference
// applies tril AFTER softmax, no renormalization). Online m/l over all 32
// k-tiles; PV accumulated only for k-tiles with k0 <= q0; diagonal tile
// masked elementwise. 64 q-rows per block, 256 threads, 4x4 per thread.
// ---------------------------------------------------------------------------
__global__ __launch_bounds__(256) void attn_kernel(
    const float* __restrict__ Q, const float* __restrict__ K, const float* __restrict__ V,
    float* __restrict__ out)
{
    const int qt = blockIdx.x, h = blockIdx.y, b = blockIdx.z;
    const int q0 = qt * 64;
    __shared__ float Qs[64][68], Ks[64][68], Vs[64][68], Ps[64][68];
    const int t  = threadIdx.x;
    const int tg = t >> 4;
    const int tc = t & 15;
    const size_t headoff = ((size_t)(b * HH + h)) * SS * DHH;

    // stage Q, pre-scaled by 1/sqrt(DH) = 0.125
#pragma unroll
    for (int i = 0; i < 4; i++) {
        int flat = t + 256 * i;
        int row  = flat >> 4;
        int c4   = flat & 15;
        float4 q = *(const float4*)(Q + headoff + (size_t)(q0 + row) * DHH + c4 * 4);
        q.x *= 0.125f; q.y *= 0.125f; q.z *= 0.125f; q.w *= 0.125f;
        *(float4*)&Qs[row][c4 * 4] = q;
    }

    float o[4][4];
    float mrow[4], lrow[4];
#pragma unroll
    for (int ri = 0; ri < 4; ri++) {
        mrow[ri] = -3.0e38f;
        lrow[ri] = 0.f;
#pragma unroll
        for (int ei = 0; ei < 4; ei++) o[ri][ei] = 0.f;
    }

    for (int kt = 0; kt < SS / 64; kt++) {
        const int  k0    = kt * 64;
        const bool do_pv = (k0 <= q0);
        __syncthreads();   // previous iteration done reading Ks/Vs/Ps
#pragma unroll
        for (int i = 0; i < 4; i++) {
            int flat = t + 256 * i;
            int row  = flat >> 4;
            int c4   = flat & 15;
            *(float4*)&Ks[row][c4 * 4] =
                *(const float4*)(K + headoff + (size_t)(k0 + row) * DHH + c4 * 4);
            if (do_pv)
                *(float4*)&Vs[row][c4 * 4] =
                    *(const float4*)(V + headoff + (size_t)(k0 + row) * DHH + c4 * 4);
        }
        __syncthreads();

        // scores s[ri][ci] = (Q/8) . K  for row tg+16ri, col tc+16ci
        float s[4][4];
#pragma unroll
        for (int ri = 0; ri < 4; ri++)
#pragma unroll
            for (int ci = 0; ci < 4; ci++) s[ri][ci] = 0.f;

        for (int dd = 0; dd < 64; dd += 4) {
            float4 qv[4], kv[4];
#pragma unroll
            for (int ri = 0; ri < 4; ri++) qv[ri] = *(float4*)&Qs[tg + 16 * ri][dd];
#pragma unroll
            for (int ci = 0; ci < 4; ci++) kv[ci] = *(float4*)&Ks[tc + 16 * ci][dd];
#pragma unroll
            for (int ri = 0; ri < 4; ri++)
#pragma unroll
                for (int ci = 0; ci < 4; ci++)
                    s[ri][ci] += qv[ri].x * kv[ci].x + qv[ri].y * kv[ci].y
                               + qv[ri].z * kv[ci].z + qv[ri].w * kv[ci].w;
        }

        // online softmax stats over the FULL row (no mask here)
#pragma unroll
        for (int ri = 0; ri < 4; ri++) {
            float pm = fmaxf(fmaxf(s[ri][0], s[ri][1]), fmaxf(s[ri][2], s[ri][3]));
            pm = fmaxf(pm, __shfl_xor(pm, 1, 16));
            pm = fmaxf(pm, __shfl_xor(pm, 2, 16));
            pm = fmaxf(pm, __shfl_xor(pm, 4, 16));
            pm = fmaxf(pm, __shfl_xor(pm, 8, 16));
            float nm  = fmaxf(mrow[ri], pm);
            float fac = __expf(mrow[ri] - nm);
            float psum = 0.f;
#pragma unroll
            for (int ci = 0; ci < 4; ci++) {
                s[ri][ci] = __expf(s[ri][ci] - nm);
                psum += s[ri][ci];
            }
            psum += __shfl_xor(psum, 1, 16);
            psum += __shfl_xor(psum, 2, 16);
            psum += __shfl_xor(psum, 4, 16);
            psum += __shfl_xor(psum, 8, 16);
            lrow[ri] = lrow[ri] * fac + psum;
            mrow[ri] = nm;
#pragma unroll
            for (int ei = 0; ei < 4; ei++) o[ri][ei] *= fac;
        }

        if (do_pv) {
            const bool diag = (k0 == q0);
            // write (masked) P to LDS for the cross-thread PV product
#pragma unroll
            for (int ri = 0; ri < 4; ri++) {
#pragma unroll
                for (int ci = 0; ci < 4; ci++) {
                    float pv = s[ri][ci];
                    if (diag && (tc + 16 * ci > tg + 16 * ri)) pv = 0.f;
                    Ps[tg + 16 * ri][tc + 16 * ci] = pv;
                }
            }
            __syncthreads();
            for (int k = 0; k < 64; k += 4) {
                float4 pq[4];
                float  pa[4][4];
#pragma unroll
                for (int ri = 0; ri < 4; ri++) {
                    pq[ri] = *(float4*)&Ps[tg + 16 * ri][k];
                    pa[ri][0] = pq[ri].x; pa[ri][1] = pq[ri].y;
                    pa[ri][2] = pq[ri].z; pa[ri][3] = pq[ri].w;
                }
#pragma unroll
                for (int kk = 0; kk < 4; kk++) {
                    float vw[4];
#pragma unroll
                    for (int ei = 0; ei < 4; ei++) vw[ei] = Vs[k + kk][tc + 16 * ei];
#pragma unroll
                    for (int ri = 0; ri < 4; ri++)
#pragma unroll
                        for (int ei = 0; ei < 4; ei++)
                            o[ri][ei] += pa[ri][kk] * vw[ei];
                }
            }
        }
    }

    // epilogue: divide by full-row softmax denominator, write [B,S,H*DH]
#pragma unroll
    for (int ri = 0; ri < 4; ri++) {
        float inv = 1.0f / lrow[ri];
        int r = q0 + tg + 16 * ri;
#pragma unroll
        for (int ei = 0; ei < 4; ei++) {
            out[((size_t)(b * SS) + r) * (HH * DHH) + h * DHH + tc + 16 * ei] =
                o[ri][ei] * inv;
        }
    }
}

extern "C" void kernel_launch(void* const* d_in, const int* in_sizes, int n_in,
                              void* d_out, int out_size, void* d_ws, size_t ws_size,
                              hipStream_t stream) {
    const float* X  = (const float*)d_in[0];
    const float* Wq = (const float*)d_in[1];
    const float* Wk = (const float*)d_in[2];
    const float* Wv = (const float*)d_in[3];
    const float* bq = (const float*)d_in[4];
    const float* bk = (const float*)d_in[5];
    const float* bv = (const float*)d_in[6];
    float* out = (float*)d_out;

    // workspace: Q,K,V fp32 [B,H,S,DH] = 3 * 16.78 MB = 50.3 MB
    float* Qw = (float*)d_ws;
    float* Kw = Qw + (size_t)BB * HH * SS * DHH;
    float* Vw = Kw + (size_t)BB * HH * SS * DHH;

    dim3 grid(SS / 64, HH, BB);
    dim3 block(256);
    proj_kernel<<<grid, block, 0, stream>>>(X, Wq, Wk, Wv, bq, bk, bv, Qw, Kw, Vw);
    attn_kernel<<<grid, block, 0, stream>>>(Qw, Kw, Vw, out);
}

// Round 3
// 189.338 us; speedup vs baseline: 5.2469x; 5.2469x over previous
//
#include <hip/hip_runtime.h>
#include <hip/hip_bf16.h>

#define DD   1024
#define HH   16
#define DHH  64
#define SS   2048
#define BB   2

using f32x4 = __attribute__((ext_vector_type(4))) float;
using s16x8 = __attribute__((ext_vector_type(8))) short;
using s16x4 = __attribute__((ext_vector_type(4))) short;

// round-to-nearest-even f32 -> bf16 bits
static __device__ __forceinline__ unsigned short f2bf(float x) {
    unsigned u = __float_as_uint(x);
    unsigned r = 0x7fffu + ((u >> 16) & 1u);
    return (unsigned short)((u + r) >> 16);
}
static __device__ __forceinline__ float bf2f(unsigned short h) {
    return __uint_as_float(((unsigned)h) << 16);
}

// async 16B global->LDS (linear dest: wave-uniform base + lane*16)
static __device__ __forceinline__ void glds16(const void* g, void* l) {
    __builtin_amdgcn_global_load_lds(
        (const __attribute__((address_space(1))) unsigned int*)g,
        (__attribute__((address_space(3))) unsigned int*)l, 16, 0, 0);
}

// byte offset in a [rows][64 bf16] (=128B/row) LDS tile, XOR-swizzled 16B blocks
static __device__ __forceinline__ int swz(int row, int blk) {
    return row * 128 + (((blk) ^ (row & 7)) << 4);
}

#define MFMA(a, b, c) __builtin_amdgcn_mfma_f32_16x16x32_bf16((a), (b), (c), 0, 0, 0)

// ws byte offsets
#define WTHI_OFF 0u
#define WTLO_OFF 6291456u      /* mats 0,1 only */
#define VT_OFF   6291456u      /* overlays Wtlo: live only after K2a is done */
#define QHI_OFF  14680064u
#define QLO_OFF  23068672u
#define KHI_OFF  31457280u
#define KLO_OFF  39845888u
/* total = 48234496 bytes */

// ---------------------------------------------------------------------------
// K1: split W into bf16 hi/lo and transpose to Wt[mat*16+h][e][d] (row = n, 1024 d)
// ---------------------------------------------------------------------------
__global__ __launch_bounds__(256, 2) void wsplit_kernel(
    const float* __restrict__ Wq, const float* __restrict__ Wk, const float* __restrict__ Wv,
    short* __restrict__ Wthi, short* __restrict__ Wtlo)
{
    const int dt = blockIdx.x;        // d-tile (16)
    const int mh = blockIdx.y;        // mat*16+h (48)
    const int mat = mh >> 4, h = mh & 15;
    const int d0 = dt * 64;
    const float* Wm = (mat == 0 ? Wq : (mat == 1 ? Wk : Wv)) + (size_t)h * DD * DHH;

    __shared__ float Ws[64][65];
    const int t = threadIdx.x;

#pragma unroll
    for (int i = 0; i < 4; i++) {
        int f = t + 256 * i;
        int row = f >> 4;          // d-local
        int c4  = f & 15;          // e quad
        float4 v = *(const float4*)(Wm + (size_t)(d0 + row) * DHH + c4 * 4);
        Ws[row][c4 * 4 + 0] = v.x;
        Ws[row][c4 * 4 + 1] = v.y;
        Ws[row][c4 * 4 + 2] = v.z;
        Ws[row][c4 * 4 + 3] = v.w;
    }
    __syncthreads();

    const int e = t >> 2, dq = t & 3;
    s16x8 hi0, hi1, lo0, lo1;
#pragma unroll
    for (int i = 0; i < 8; i++) {
        float v = Ws[dq * 16 + i][e];
        unsigned short hb = f2bf(v);
        hi0[i] = (short)hb; lo0[i] = (short)f2bf(v - bf2f(hb));
    }
#pragma unroll
    for (int i = 0; i < 8; i++) {
        float v = Ws[dq * 16 + 8 + i][e];
        unsigned short hb = f2bf(v);
        hi1[i] = (short)hb; lo1[i] = (short)f2bf(v - bf2f(hb));
    }
    size_t off = ((size_t)(mh * 64 + e)) * DD + d0 + dq * 16;
    *(s16x8*)(Wthi + off)     = hi0;
    *(s16x8*)(Wthi + off + 8) = hi1;
    if (mat < 2) {
        *(s16x8*)(Wtlo + off)     = lo0;
        *(s16x8*)(Wtlo + off + 8) = lo1;
    }
}

// ---------------------------------------------------------------------------
// K2a: Q/K projection. A = Wt rows (n), B = X cols (s), 3-product split bf16.
// Block tile 128n x 128s, K-step 64. Epilogue writes hi/lo, Q pre-scaled 1/8.
// ---------------------------------------------------------------------------
__global__ __launch_bounds__(256, 2) void proj_qk_kernel(
    const float* __restrict__ X,
    const short* __restrict__ Wthi, const short* __restrict__ Wtlo,
    const float* __restrict__ bq, const float* __restrict__ bk,
    short* __restrict__ QhiG, short* __restrict__ QloG,
    short* __restrict__ KhiG, short* __restrict__ KloG)
{
    const int s0 = blockIdx.x * 128;
    const int n0 = blockIdx.y * 128;
    __shared__ __align__(16) char smem[65536];
    const int WHI = 0, WLO = 16384, XHI = 32768, XLO = 49152;

    const int t = threadIdx.x;
    const int w = t >> 6, lane = t & 63, g = lane >> 4, ln = lane & 15;
    const int wm = w >> 1, wn = w & 1;

    f32x4 acc[4][4];
#pragma unroll
    for (int i = 0; i < 4; i++)
#pragma unroll
        for (int j = 0; j < 4; j++) acc[i][j] = (f32x4){0.f, 0.f, 0.f, 0.f};

    for (int d0 = 0; d0 < DD; d0 += 64) {
        if (d0) __syncthreads();
        // stage W hi/lo via global_load_lds (pre-swizzled source)
#pragma unroll
        for (int p = 0; p < 4; p++) {
            int idx = p * 256 + t;
            int row = idx >> 3, blk = idx & 7;
            size_t so = (size_t)(n0 + row) * DD + d0 + ((blk ^ (row & 7)) * 8);
            glds16(Wthi + so, smem + WHI + idx * 16);
            glds16(Wtlo + so, smem + WLO + idx * 16);
        }
        // stage X: f32 -> hi/lo bf16, swizzled ds writes
#pragma unroll
        for (int p = 0; p < 4; p++) {
            int idx = p * 256 + t;
            int row = idx >> 3, blk = idx & 7;
            const float* xp = X + (size_t)(s0 + row) * DD + d0 + blk * 8;
            float4 va = *(const float4*)xp;
            float4 vb = *(const float4*)(xp + 4);
            float v[8] = {va.x, va.y, va.z, va.w, vb.x, vb.y, vb.z, vb.w};
            s16x8 hi, lo;
#pragma unroll
            for (int i = 0; i < 8; i++) {
                unsigned short hb = f2bf(v[i]);
                hi[i] = (short)hb; lo[i] = (short)f2bf(v[i] - bf2f(hb));
            }
            *(s16x8*)(smem + XHI + swz(row, blk)) = hi;
            *(s16x8*)(smem + XLO + swz(row, blk)) = lo;
        }
        __syncthreads();

        s16x8 bxh[4][2], bxl[4][2];
#pragma unroll
        for (int nf = 0; nf < 4; nf++)
#pragma unroll
            for (int kst = 0; kst < 2; kst++) {
                int off = swz(64 * wn + nf * 16 + ln, kst * 4 + g);
                bxh[nf][kst] = *(const s16x8*)(smem + XHI + off);
                bxl[nf][kst] = *(const s16x8*)(smem + XLO + off);
            }
#pragma unroll
        for (int mf = 0; mf < 4; mf++) {
            s16x8 awh[2], awl[2];
#pragma unroll
            for (int kst = 0; kst < 2; kst++) {
                int off = swz(64 * wm + mf * 16 + ln, kst * 4 + g);
                awh[kst] = *(const s16x8*)(smem + WHI + off);
                awl[kst] = *(const s16x8*)(smem + WLO + off);
            }
#pragma unroll
            for (int kst = 0; kst < 2; kst++)
#pragma unroll
                for (int nf = 0; nf < 4; nf++) {
                    acc[mf][nf] = MFMA(awh[kst], bxh[nf][kst], acc[mf][nf]);
                    acc[mf][nf] = MFMA(awh[kst], bxl[nf][kst], acc[mf][nf]);
                    acc[mf][nf] = MFMA(awl[kst], bxh[nf][kst], acc[mf][nf]);
                }
        }
    }

    // epilogue: C row = n (4 consecutive e per lane), col = s
    const int mat = n0 >> 10;                       // 0=Q, 1=K
    const int h = ((n0 + 64 * wm) >> 6) & 15;
    const float* bptr = (mat ? bk : bq) + h * 64;
    short* HiP = mat ? KhiG : QhiG;
    short* LoP = mat ? KloG : QloG;
    const float scale = mat ? 1.0f : 0.125f;

#pragma unroll
    for (int nf = 0; nf < 4; nf++) {
        int sg = s0 + 64 * wn + nf * 16 + ln;
        int bidx = sg >> 11, sr = sg & (SS - 1);
        size_t rowbase = ((size_t)((bidx * HH + h) * SS + sr)) * DHH;
#pragma unroll
        for (int mf = 0; mf < 4; mf++) {
            float4 bias = *(const float4*)(bptr + mf * 16 + g * 4);
            float bb[4] = {bias.x, bias.y, bias.z, bias.w};
            s16x4 hi4, lo4;
#pragma unroll
            for (int r = 0; r < 4; r++) {
                float vv = (acc[mf][nf][r] + bb[r]) * scale;
                unsigned short hb = f2bf(vv);
                hi4[r] = (short)hb; lo4[r] = (short)f2bf(vv - bf2f(hb));
            }
            size_t off = rowbase + mf * 16 + g * 4;
            *(s16x4*)(HiP + off) = hi4;
            *(s16x4*)(LoP + off) = lo4;
        }
    }
}

// ---------------------------------------------------------------------------
// K2b: V projection. A = X rows (s), B = Wv cols (e), single product.
// Epilogue writes V TRANSPOSED: Vt[b,h,e,s] (4 consecutive s per lane).
// ---------------------------------------------------------------------------
__global__ __launch_bounds__(256, 2) void proj_v_kernel(
    const float* __restrict__ X,
    const short* __restrict__ Wthi,
    const float* __restrict__ bv,
    short* __restrict__ VtG)
{
    const int s0 = blockIdx.x * 128;
    const int n0 = blockIdx.y * 128;     // within mat-2 block [0,1024)
    __shared__ __align__(16) char smem[32768];
    const int XHIo = 0, WHIo = 16384;

    const int t = threadIdx.x;
    const int w = t >> 6, lane = t & 63, g = lane >> 4, ln = lane & 15;
    const int wm = w >> 1, wn = w & 1;

    f32x4 acc[4][4];
#pragma unroll
    for (int i = 0; i < 4; i++)
#pragma unroll
        for (int j = 0; j < 4; j++) acc[i][j] = (f32x4){0.f, 0.f, 0.f, 0.f};

    for (int d0 = 0; d0 < DD; d0 += 64) {
        if (d0) __syncthreads();
#pragma unroll
        for (int p = 0; p < 4; p++) {
            int idx = p * 256 + t;
            int row = idx >> 3, blk = idx & 7;
            size_t so = (size_t)(2048 + n0 + row) * DD + d0 + ((blk ^ (row & 7)) * 8);
            glds16(Wthi + so, smem + WHIo + idx * 16);
        }
#pragma unroll
        for (int p = 0; p < 4; p++) {
            int idx = p * 256 + t;
            int row = idx >> 3, blk = idx & 7;
            const float* xp = X + (size_t)(s0 + row) * DD + d0 + blk * 8;
            float4 va = *(const float4*)xp;
            float4 vb = *(const float4*)(xp + 4);
            float v[8] = {va.x, va.y, va.z, va.w, vb.x, vb.y, vb.z, vb.w};
            s16x8 hi;
#pragma unroll
            for (int i = 0; i < 8; i++) hi[i] = (short)f2bf(v[i]);
            *(s16x8*)(smem + XHIo + swz(row, blk)) = hi;
        }
        __syncthreads();

        s16x8 bw[4][2];
#pragma unroll
        for (int nf = 0; nf < 4; nf++)
#pragma unroll
            for (int kst = 0; kst < 2; kst++)
                bw[nf][kst] = *(const s16x8*)(smem + WHIo + swz(64 * wn + nf * 16 + ln, kst * 4 + g));
#pragma unroll
        for (int mf = 0; mf < 4; mf++) {
            s16x8 ax[2];
#pragma unroll
            for (int kst = 0; kst < 2; kst++)
                ax[kst] = *(const s16x8*)(smem + XHIo + swz(64 * wm + mf * 16 + ln, kst * 4 + g));
#pragma unroll
            for (int kst = 0; kst < 2; kst++)
#pragma unroll
                for (int nf = 0; nf < 4; nf++)
                    acc[mf][nf] = MFMA(ax[kst], bw[nf][kst], acc[mf][nf]);
        }
    }

    // epilogue: C row = s (4 consecutive s per lane), col = e
    const int h = ((n0 + 64 * wn) >> 6) & 15;
#pragma unroll
    for (int nf = 0; nf < 4; nf++) {
        int e = nf * 16 + ln;
        float bvv = bv[h * 64 + e];
#pragma unroll
        for (int mf = 0; mf < 4; mf++) {
            int sgb = s0 + 64 * wm + mf * 16 + g * 4;   // 4 consecutive s
            int bidx = sgb >> 11, sr = sgb & (SS - 1);
            s16x4 v4;
#pragma unroll
            for (int r = 0; r < 4; r++) v4[r] = (short)f2bf(acc[mf][nf][r] + bvv);
            *(s16x4*)(VtG + ((size_t)((bidx * HH + h) * DHH + e)) * SS + sr) = v4;
        }
    }
}

// ---------------------------------------------------------------------------
// K3: attention. 128 q-rows/block, 4 waves (32 q each). Swapped QK^T (A=K,B=Q)
// -> S^T; full-row online softmax stats; tril mask on P only; PV as Z^T=Vt*P^T.
// ---------------------------------------------------------------------------
__global__ __launch_bounds__(256, 2) void attn_kernel(
    const short* __restrict__ QhiG, const short* __restrict__ QloG,
    const short* __restrict__ KhiG, const short* __restrict__ KloG,
    const short* __restrict__ VtG,
    float* __restrict__ out)
{
    const int qt = blockIdx.x, h = blockIdx.y, b = blockIdx.z;
    const int q0 = qt * 128;
    const size_t ho = (size_t)(b * HH + h) * SS * DHH;   // same stride for Vt

    __shared__ __align__(16) char smem[73728];
    const int QHI = 0, QLO = 16384, KHI = 32768, KLO = 40960, VT = 49152, PS = 57344;

    const int t = threadIdx.x;
    const int w = t >> 6, lane = t & 63, g = lane >> 4, ln = lane & 15;

    // stage Q hi/lo (once)
#pragma unroll
    for (int p = 0; p < 4; p++) {
        int idx = p * 256 + t;
        int row = idx >> 3, blk = idx & 7;
        size_t so = ho + (size_t)(q0 + row) * DHH + ((blk ^ (row & 7)) * 8);
        glds16(QhiG + so, smem + QHI + idx * 16);
        glds16(QloG + so, smem + QLO + idx * 16);
    }
    __syncthreads();

    s16x8 qh[2][2], ql[2][2];
#pragma unroll
    for (int nf = 0; nf < 2; nf++)
#pragma unroll
        for (int kst = 0; kst < 2; kst++) {
            int off = swz(32 * w + nf * 16 + ln, kst * 4 + g);
            qh[nf][kst] = *(const s16x8*)(smem + QHI + off);
            ql[nf][kst] = *(const s16x8*)(smem + QLO + off);
        }

    f32x4 o[4][2];
#pragma unroll
    for (int i = 0; i < 4; i++)
#pragma unroll
        for (int j = 0; j < 2; j++) o[i][j] = (f32x4){0.f, 0.f, 0.f, 0.f};
    float m[2] = {-3.0e38f, -3.0e38f}, l[2] = {0.f, 0.f};

    for (int kt = 0; kt < SS / 64; kt++) {
        const int k0 = kt * 64;
        const bool do_pv = (kt <= 2 * qt + 1);
        __syncthreads();   // previous tile's reads of K/V done
#pragma unroll
        for (int p = 0; p < 2; p++) {
            int idx = p * 256 + t;
            int row = idx >> 3, blk = idx & 7;
            int soff = (blk ^ (row & 7)) * 8;
            glds16(KhiG + ho + (size_t)(k0 + row) * DHH + soff, smem + KHI + idx * 16);
            glds16(KloG + ho + (size_t)(k0 + row) * DHH + soff, smem + KLO + idx * 16);
            if (do_pv)
                glds16(VtG + ho + (size_t)row * SS + k0 + soff, smem + VT + idx * 16);
        }
        __syncthreads();

        // S^T tile: rows = k (64), cols = q (32 per wave)
        f32x4 s[4][2];
#pragma unroll
        for (int i = 0; i < 4; i++)
#pragma unroll
            for (int j = 0; j < 2; j++) s[i][j] = (f32x4){0.f, 0.f, 0.f, 0.f};

#pragma unroll
        for (int kst = 0; kst < 2; kst++) {
            s16x8 akh[4], akl[4];
#pragma unroll
            for (int mf = 0; mf < 4; mf++) {
                int off = swz(mf * 16 + ln, kst * 4 + g);
                akh[mf] = *(const s16x8*)(smem + KHI + off);
                akl[mf] = *(const s16x8*)(smem + KLO + off);
            }
#pragma unroll
            for (int mf = 0; mf < 4; mf++)
#pragma unroll
                for (int nf = 0; nf < 2; nf++) {
                    s[mf][nf] = MFMA(akh[mf], qh[nf][kst], s[mf][nf]);
                    s[mf][nf] = MFMA(akh[mf], ql[nf][kst], s[mf][nf]);
                    s[mf][nf] = MFMA(akl[mf], qh[nf][kst], s[mf][nf]);
                }
        }

        // online softmax over FULL row (reference masks AFTER softmax)
#pragma unroll
        for (int nf = 0; nf < 2; nf++) {
            float pm = s[0][nf][0];
#pragma unroll
            for (int mf = 0; mf < 4; mf++)
#pragma unroll
                for (int r = 0; r < 4; r++) pm = fmaxf(pm, s[mf][nf][r]);
            pm = fmaxf(pm, __shfl_xor(pm, 16));
            pm = fmaxf(pm, __shfl_xor(pm, 32));
            float nm = fmaxf(m[nf], pm);
            float fac = __expf(m[nf] - nm);
            float ps = 0.f;
#pragma unroll
            for (int mf = 0; mf < 4; mf++)
#pragma unroll
                for (int r = 0; r < 4; r++) {
                    float pe = __expf(s[mf][nf][r] - nm);
                    s[mf][nf][r] = pe;
                    ps += pe;
                }
            ps += __shfl_xor(ps, 16);
            ps += __shfl_xor(ps, 32);
            l[nf] = l[nf] * fac + ps;
            m[nf] = nm;
#pragma unroll
            for (int mf = 0; mf < 4; mf++)
#pragma unroll
                for (int r = 0; r < 4; r++) o[mf][nf][r] *= fac;
        }

        if (do_pv) {
            // write masked P^T (bf16) to LDS, packed 4-per-b64
#pragma unroll
            for (int nf = 0; nf < 2; nf++) {
                int qrow = 32 * w + nf * 16 + ln;
                int qg = q0 + qrow;
#pragma unroll
                for (int mf = 0; mf < 4; mf++) {
                    int kb = k0 + mf * 16 + g * 4;
                    s16x4 pv;
#pragma unroll
                    for (int r = 0; r < 4; r++) {
                        float pp = (kb + r > qg) ? 0.f : s[mf][nf][r];
                        pv[r] = (short)f2bf(pp);
                    }
                    int byte = PS + qrow * 128 + ((((mf * 2 + (g >> 1)) ^ (qrow & 7))) << 4) + (g & 1) * 8;
                    *(s16x4*)(smem + byte) = pv;
                }
            }
            asm volatile("s_waitcnt lgkmcnt(0)" ::: "memory");
            __builtin_amdgcn_sched_barrier(0);
#pragma unroll
            for (int kst = 0; kst < 2; kst++) {
                s16x8 av[4], bp[2];
#pragma unroll
                for (int mf = 0; mf < 4; mf++)
                    av[mf] = *(const s16x8*)(smem + VT + swz(mf * 16 + ln, kst * 4 + g));
#pragma unroll
                for (int nf = 0; nf < 2; nf++)
                    bp[nf] = *(const s16x8*)(smem + PS + swz(32 * w + nf * 16 + ln, kst * 4 + g));
#pragma unroll
                for (int mf = 0; mf < 4; mf++)
#pragma unroll
                    for (int nf = 0; nf < 2; nf++)
                        o[mf][nf] = MFMA(av[mf], bp[nf], o[mf][nf]);
            }
        }
    }

    // epilogue: Z^T rows = e, cols = q -> out[b][q][h*64+e], float4 per frag
#pragma unroll
    for (int nf = 0; nf < 2; nf++) {
        float inv = 1.0f / l[nf];
        int qg = q0 + 32 * w + nf * 16 + ln;
        float* op = out + ((size_t)(b * SS + qg)) * (HH * DHH) + h * DHH;
#pragma unroll
        for (int mf = 0; mf < 4; mf++) {
            float4 vv = {o[mf][nf][0] * inv, o[mf][nf][1] * inv,
                         o[mf][nf][2] * inv, o[mf][nf][3] * inv};
            *(float4*)(op + mf * 16 + g * 4) = vv;
        }
    }
}

extern "C" void kernel_launch(void* const* d_in, const int* in_sizes, int n_in,
                              void* d_out, int out_size, void* d_ws, size_t ws_size,
                              hipStream_t stream) {
    const float* X  = (const float*)d_in[0];
    const float* Wq = (const float*)d_in[1];
    const float* Wk = (const float*)d_in[2];
    const float* Wv = (const float*)d_in[3];
    const float* bq = (const float*)d_in[4];
    const float* bk = (const float*)d_in[5];
    const float* bv = (const float*)d_in[6];
    float* out = (float*)d_out;

    char* wsb = (char*)d_ws;
    short* Wthi = (short*)(wsb + WTHI_OFF);
    short* Wtlo = (short*)(wsb + WTLO_OFF);
    short* Vt   = (short*)(wsb + VT_OFF);     // overlays Wtlo (sequential lifetime)
    short* Qhi  = (short*)(wsb + QHI_OFF);
    short* Qlo  = (short*)(wsb + QLO_OFF);
    short* Khi  = (short*)(wsb + KHI_OFF);
    short* Klo  = (short*)(wsb + KLO_OFF);

    wsplit_kernel<<<dim3(16, 48), 256, 0, stream>>>(Wq, Wk, Wv, Wthi, Wtlo);
    proj_qk_kernel<<<dim3(32, 16), 256, 0, stream>>>(X, Wthi, Wtlo, bq, bk,
                                                     Qhi, Qlo, Khi, Klo);
    proj_v_kernel<<<dim3(32, 8), 256, 0, stream>>>(X, Wthi, bv, Vt);
    attn_kernel<<<dim3(16, 16, 2), 256, 0, stream>>>(Qhi, Qlo, Khi, Klo, Vt, out);
}